// Round 7
// baseline (36291.501 us; speedup 1.0000x reference)
//
#include <hip/hip_runtime.h>
#include <hip/hip_bf16.h>
#include <cstdint>
#include <cstddef>

// Problem constants
#define B_SZ   256
#define T_SZ   2049
#define D_SZ   64
#define H_SZ   64
#define MLP_SZ 128
#define NI_SZ  128
#define SEG    16
#define L_SZ   2080
#define OUT_SZ 10

// Pipeline shapes
#define NC      16                 // intervals per chunk
#define NCC     (NI_SZ / NC)       // 8 chunks
#define MROWS_C (NC * B_SZ)        // 4096 GEMM rows per chunk
#define NCOLS   8320               // 8192 (n=d*128+m) + 64 (b2) + 64 pad
#define KDIM    L_SZ               // 2080
#define TILES_M (MROWS_C / 128)    // 32
#define TILES_N (NCOLS / 128)      // 65
#define NTILES  (TILES_M * TILES_N)// 2080
#define WORKERS 640
#define ODEB    128                // ode/logsig blocks, 2 batches each
#define GRID_SZ (WORKERS + ODEB)   // 768 = 3 blocks/CU (guaranteed by launch_bounds)

typedef _Float16 f16x8 __attribute__((ext_vector_type(8)));
typedef float    f32x4 __attribute__((ext_vector_type(4)));

struct Flags {
    int bmat_done;
    int ls_done[NCC];
    int gemm_done[NCC];
    int ode_done[NCC];
    int tile_ctr[NCC];
};

union SharedU {
    struct { unsigned short As[128 * 32]; unsigned short Bs[128 * 32]; } g;   // 16 KB
    struct { float seg[SEG + 1][D_SZ]; float cum[SEG][D_SZ];
             float dlt[SEG][D_SZ];     float Mm[D_SZ][D_SZ + 1]; } l;         // 29.2 KB
    struct { float ysw[4][D_SZ]; float part[2][4][D_SZ]; float xb[D_SZ]; } o; // 4.5 KB
};

__device__ __forceinline__ float rlane(float v, int l) {
    return __uint_as_float(__builtin_amdgcn_readlane(__float_as_uint(v), l));
}

// all threads call; t0 fences + releases
__device__ __forceinline__ void sig_release(int* p) {
    __syncthreads();
    if (threadIdx.x == 0) {
        __threadfence();
        __hip_atomic_fetch_add(p, 1, __ATOMIC_RELEASE, __HIP_MEMORY_SCOPE_AGENT);
    }
}
// all threads call; t0 spins with acquire, then block proceeds
__device__ __forceinline__ void wait_acquire(int* p, int target) {
    if (threadIdx.x == 0) {
        while (__hip_atomic_load(p, __ATOMIC_ACQUIRE, __HIP_MEMORY_SCOPE_AGENT) < target)
            __builtin_amdgcn_s_sleep(2);
        __threadfence();
    }
    __syncthreads();
}

// ---------------------------------------------------------------------------
// One logsig job (interval n_global, batch b) -> LS chunk row sl*256+b. 256 thr.
// ---------------------------------------------------------------------------
__device__ void logsig_job(const float* __restrict__ X, _Float16* __restrict__ LSc,
                           int n_global, int sl, int b, SharedU& sh) {
    const int t = threadIdx.x;
    __syncthreads();                       // protect union vs previous phase
    const float* Xp = X + ((size_t)b * T_SZ + (size_t)n_global * SEG) * D_SZ;
    for (int i = t; i < (SEG + 1) * D_SZ / 4; i += 256)
        ((float4*)&sh.l.seg[0][0])[i] = ((const float4*)Xp)[i];
    __syncthreads();
    for (int i = t; i < SEG * D_SZ; i += 256) {
        const int k = i >> 6, d = i & 63;
        sh.l.cum[k][d] = sh.l.seg[k][d] - sh.l.seg[0][d];
        sh.l.dlt[k][d] = sh.l.seg[k + 1][d] - sh.l.seg[k][d];
    }
    __syncthreads();

    const int ti = t >> 4, tj = t & 15;
    const int i0 = ti * 4, j0 = tj * 4;
    float m4[4][4] = {};
#pragma unroll
    for (int k = 0; k < SEG; ++k) {
        const float4 ci = *(const float4*)&sh.l.cum[k][i0];
        const float4 dj = *(const float4*)&sh.l.dlt[k][j0];
        const float* cip = (const float*)&ci;
        const float* djp = (const float*)&dj;
#pragma unroll
        for (int a = 0; a < 4; ++a)
#pragma unroll
            for (int c2 = 0; c2 < 4; ++c2)
                m4[a][c2] += cip[a] * djp[c2];
    }
#pragma unroll
    for (int a = 0; a < 4; ++a)
#pragma unroll
        for (int c2 = 0; c2 < 4; ++c2)
            sh.l.Mm[i0 + a][j0 + c2] = m4[a][c2];
    __syncthreads();

    _Float16* out = LSc + (size_t)(sl * B_SZ + b) * KDIM;
    if (t < D_SZ) out[t] = (_Float16)(sh.l.seg[SEG][t] - sh.l.seg[0][t]);
    if (tj >= ti) {
#pragma unroll
        for (int a = 0; a < 4; ++a) {
            const int i = i0 + a;
#pragma unroll
            for (int c2 = 0; c2 < 4; ++c2) {
                const int j = j0 + c2;
                if (j > i) {
                    const int p = 63 * i - (i * (i - 1)) / 2 + (j - i - 1);
                    out[D_SZ + p] = (_Float16)(0.5f * (m4[a][c2] - sh.l.Mm[j][i]));
                }
            }
        }
    }
    __syncthreads();
}

// ---------------------------------------------------------------------------
// One 128x128 GEMM tile (m97 structure). 256 thr.
// ---------------------------------------------------------------------------
__device__ void gemm_tile(const unsigned short* __restrict__ A,
                          const unsigned short* __restrict__ Bm,
                          _Float16* __restrict__ C, int bx, int by, SharedU& sh) {
    constexpr int K = KDIM, N = NCOLS;
    const int t = threadIdx.x;
    const int lane = t & 63;
    const int w = t >> 6;
    const int wm = w & 1, wn = w >> 1;
    const int tileM = bx * 128;
    const int tileN = by * 128;

    const int c0 = w * 2, c1 = c0 + 1;
    const int rs0 = c0 * 16 + (lane >> 2);
    const int rs1 = c1 * 16 + (lane >> 2);
    const int kc = (((lane & 3) ^ ((lane >> 2) & 3))) * 8;

    const unsigned short* gA0 = A + (size_t)(tileM + rs0) * K + kc;
    const unsigned short* gA1 = A + (size_t)(tileM + rs1) * K + kc;
    const unsigned short* gB0 = Bm + (size_t)(tileN + rs0) * K + kc;
    const unsigned short* gB1 = Bm + (size_t)(tileN + rs1) * K + kc;
    unsigned short* lA0 = sh.g.As + c0 * 512 + lane * 8;
    unsigned short* lA1 = sh.g.As + c1 * 512 + lane * 8;
    unsigned short* lB0 = sh.g.Bs + c0 * 512 + lane * 8;
    unsigned short* lB1 = sh.g.Bs + c1 * 512 + lane * 8;

    f32x4 acc[4][4] = {};
    const int frow = lane & 15;
    const int fkswz = (((lane >> 4) ^ (frow & 3))) * 8;

    for (int k0 = 0; k0 < K; k0 += 32) {
        __syncthreads();
        __builtin_amdgcn_global_load_lds((__attribute__((address_space(1))) void*)(gA0 + k0),
                                         (__attribute__((address_space(3))) void*)lA0, 16, 0, 0);
        __builtin_amdgcn_global_load_lds((__attribute__((address_space(1))) void*)(gA1 + k0),
                                         (__attribute__((address_space(3))) void*)lA1, 16, 0, 0);
        __builtin_amdgcn_global_load_lds((__attribute__((address_space(1))) void*)(gB0 + k0),
                                         (__attribute__((address_space(3))) void*)lB0, 16, 0, 0);
        __builtin_amdgcn_global_load_lds((__attribute__((address_space(1))) void*)(gB1 + k0),
                                         (__attribute__((address_space(3))) void*)lB1, 16, 0, 0);
        __syncthreads();

        f16x8 af[4], bfm[4];
#pragma unroll
        for (int mi = 0; mi < 4; ++mi)
            af[mi] = *(const f16x8*)(sh.g.As + (wm * 64 + mi * 16 + frow) * 32 + fkswz);
#pragma unroll
        for (int ni = 0; ni < 4; ++ni)
            bfm[ni] = *(const f16x8*)(sh.g.Bs + (wn * 64 + ni * 16 + frow) * 32 + fkswz);
#pragma unroll
        for (int mi = 0; mi < 4; ++mi)
#pragma unroll
            for (int ni = 0; ni < 4; ++ni)
                acc[mi][ni] = __builtin_amdgcn_mfma_f32_16x16x32_f16(af[mi], bfm[ni],
                                                                     acc[mi][ni], 0, 0, 0);
    }

    const int erow = (lane >> 4) * 4;
#pragma unroll
    for (int mi = 0; mi < 4; ++mi)
#pragma unroll
        for (int ni = 0; ni < 4; ++ni) {
            const int col = tileN + wn * 64 + ni * 16 + frow;
            const size_t rbase = (size_t)(tileM + wm * 64 + mi * 16 + erow) * N + col;
#pragma unroll
            for (int r = 0; r < 4; ++r)
                C[rbase + (size_t)r * N] = (_Float16)acc[mi][ni][r];
        }
}

// ---------------------------------------------------------------------------
// Mega persistent kernel: 640 workers (Bmat build + dynamic GEMM tiles) +
// 128 ode/logsig blocks (logsig one chunk ahead; RK4 consume; final out).
// ---------------------------------------------------------------------------
__global__ __launch_bounds__(256, 3) void mega(
        const float* __restrict__ X,    const float* __restrict__ W_in,
        const float* __restrict__ b_in, const float* __restrict__ W1,
        const float* __restrict__ b1,   const float* __restrict__ W2,
        const float* __restrict__ b2,   const float* __restrict__ W_out,
        const float* __restrict__ b_out, float* __restrict__ out,
        _Float16* __restrict__ Bmat, _Float16* __restrict__ LS0, _Float16* __restrict__ LS1,
        _Float16* __restrict__ G0, _Float16* __restrict__ G1, Flags* fl) {
    __shared__ SharedU sh;
    __shared__ int s_tile;
    const int bid = blockIdx.x, t = threadIdx.x;
    _Float16* LSbuf[2] = {LS0, LS1};
    _Float16* Gbuf[2]  = {G0, G1};

    if (bid < WORKERS) {
        // ---------------- worker: Bmat build, then GEMM tiles ----------------
        for (int r = bid; r < NCOLS; r += WORKERS) {
            const float* src = nullptr;
            if (r < 8192) {
                const int d = r >> 7, m = r & 127;
                src = W2 + (size_t)m * (64 * KDIM) + (size_t)d * KDIM;
            } else if (r < 8256) {
                src = b2 + (size_t)(r - 8192) * KDIM;
            }
            _Float16* dst = Bmat + (size_t)r * KDIM;
            for (int l = t; l < KDIM; l += 256)
                dst[l] = src ? (_Float16)src[l] : (_Float16)0.0f;
        }
        sig_release(&fl->bmat_done);
        wait_acquire(&fl->bmat_done, WORKERS);

        for (int c = 0; c < NCC; ++c) {
            if (c >= 2) wait_acquire(&fl->ode_done[c - 2], ODEB);
            wait_acquire(&fl->ls_done[c], ODEB);
            const unsigned short* Ac = (const unsigned short*)LSbuf[c & 1];
            _Float16* Gc = Gbuf[c & 1];
            for (;;) {
                if (t == 0) s_tile = atomicAdd(&fl->tile_ctr[c], 1);
                __syncthreads();
                const int tile = s_tile;
                __syncthreads();
                if (tile >= NTILES) break;
                gemm_tile(Ac, (const unsigned short*)Bmat, Gc,
                          tile % TILES_M, tile / TILES_M, sh);
            }
            sig_release(&fl->gemm_done[c]);
        }
    } else {
        // ---------------- ode/logsig block: 2 batches ----------------
        const int ob = bid - WORKERS;          // 0..127
        const int lane = t & 63, w = t >> 6;
        const int j0 = w * 32 + (lane & 31);
        float w1c[D_SZ];
#pragma unroll
        for (int dd = 0; dd < D_SZ; ++dd) w1c[dd] = W1[dd * MLP_SZ + j0];
        const float b1v = b1[j0];

        float hsv[2];
#pragma unroll
        for (int e = 0; e < 2; ++e) {          // h0
            const int b = ob * 2 + e;
            __syncthreads();
            if (t < D_SZ) sh.o.xb[t] = X[(size_t)b * T_SZ * D_SZ + t];
            __syncthreads();
            float acc = b_in[lane];
            for (int k = 0; k < D_SZ; ++k) acc += sh.o.xb[k] * W_in[k * H_SZ + lane];
            hsv[e] = acc;                      // redundant across waves
        }

        // logsig(0)
        for (int i = 0; i < 32; ++i) {
            const int j = ob * 32 + i;
            logsig_job(X, LSbuf[0], (j >> 8), (j >> 8), j & 255, sh);
        }
        sig_release(&fl->ls_done[0]);

        for (int c = 0; c < NCC; ++c) {
            if (c + 1 < NCC) {                 // logsig one chunk ahead
                for (int i = 0; i < 32; ++i) {
                    const int j = ob * 32 + i;
                    const int sl = j >> 8;
                    logsig_job(X, LSbuf[(c + 1) & 1], (c + 1) * NC + sl, sl, j & 255, sh);
                }
                sig_release(&fl->ls_done[c + 1]);
            }
            wait_acquire(&fl->gemm_done[c], WORKERS);
            const _Float16* Gc = Gbuf[c & 1];

#pragma unroll 1
            for (int e = 0; e < 2; ++e) {
                const int b = ob * 2 + e;
                float h = hsv[e];
                __syncthreads();
                sh.o.ysw[w][lane] = h;
                float k_st[4];
#pragma unroll 1
                for (int s = 0; s < NC; ++s) {
                    const _Float16* Gr = Gc + (size_t)(s * B_SZ + b) * NCOLS;
                    const f16x8* gp = (const f16x8*)(Gr + lane * 128 + w * 32);
                    f16x8 pr[4];
#pragma unroll
                    for (int v = 0; v < 4; ++v) pr[v] = gp[v];
                    const float b2cur = (float)Gr[8192 + lane];
                    float gcur[32];
#pragma unroll
                    for (int v = 0; v < 4; ++v)
#pragma unroll
                        for (int ee = 0; ee < 8; ++ee) gcur[v * 8 + ee] = (float)pr[v][ee];

#pragma unroll
                    for (int st = 0; st < 4; ++st) {
                        float a = 0.0f;
#pragma unroll
                        for (int dd = 0; dd < D_SZ; dd += 4) {
                            const float4 yv = *(const float4*)&sh.o.ysw[w][dd];
                            a += yv.x * w1c[dd] + yv.y * w1c[dd + 1]
                               + yv.z * w1c[dd + 2] + yv.w * w1c[dd + 3];
                        }
                        const float x = b1v + a;
                        const float ex = __expf(2.0f * x);
                        const float z = 1.0f - 2.0f / (ex + 1.0f);
                        float a2 = 0.0f;
#pragma unroll
                        for (int q = 0; q < 32; ++q)
                            a2 += gcur[q] * rlane(z, q);
                        sh.o.part[st & 1][w][lane] = a2;
                        __syncthreads();
                        const float kv = b2cur + sh.o.part[st & 1][0][lane]
                                       + sh.o.part[st & 1][1][lane]
                                       + sh.o.part[st & 1][2][lane]
                                       + sh.o.part[st & 1][3][lane];
                        k_st[st] = kv;
                        if (st < 3) {
                            float y = h;
                            if (st == 0) y += 0.5f * kv;
                            else if (st == 1) y += 0.5f * kv;
                            else y += kv;
                            sh.o.ysw[w][lane] = y;
                        }
                    }
                    h += (k_st[0] + 2.0f * k_st[1] + 2.0f * k_st[2] + k_st[3]) * (1.0f / 6.0f);
                    sh.o.ysw[w][lane] = h;
                }
                hsv[e] = h;
                __syncthreads();
            }
            sig_release(&fl->ode_done[c]);
        }

        // final out for my 2 batches
#pragma unroll
        for (int e = 0; e < 2; ++e) {
            const int b = ob * 2 + e;
            __syncthreads();
            if (w == 0) sh.o.xb[lane] = hsv[e];
            __syncthreads();
            if (t < OUT_SZ) {
                float acc = b_out[t];
                for (int d = 0; d < D_SZ; ++d) acc += sh.o.xb[d] * W_out[d * OUT_SZ + t];
                out[b * OUT_SZ + t] = acc;
            }
        }
    }
}

extern "C" void kernel_launch(void* const* d_in, const int* in_sizes, int n_in,
                              void* d_out, int out_size, void* d_ws, size_t ws_size,
                              hipStream_t stream) {
    (void)in_sizes; (void)n_in; (void)out_size; (void)ws_size;
    const float* X     = (const float*)d_in[0];
    const float* W_in  = (const float*)d_in[1];
    const float* b_in  = (const float*)d_in[2];
    const float* W1    = (const float*)d_in[3];
    const float* b1    = (const float*)d_in[4];
    const float* W2    = (const float*)d_in[5];
    const float* b2    = (const float*)d_in[6];
    const float* W_out = (const float*)d_in[7];
    const float* b_out = (const float*)d_in[8];
    float* out = (float*)d_out;

    // workspace: flags(512B) + Bmat 34.6MB + LS dbuf 2x17.0MB + G dbuf 2x68.2MB ~ 205MB
    char* ws = (char*)d_ws;
    Flags* fl = (Flags*)ws;
    size_t off = 512;
    _Float16* Bmat = (_Float16*)(ws + off); off += (size_t)NCOLS * KDIM * 2;
    _Float16* LS0  = (_Float16*)(ws + off); off += (size_t)MROWS_C * KDIM * 2;
    _Float16* LS1  = (_Float16*)(ws + off); off += (size_t)MROWS_C * KDIM * 2;
    _Float16* G0   = (_Float16*)(ws + off); off += (size_t)MROWS_C * NCOLS * 2;
    _Float16* G1   = (_Float16*)(ws + off); off += (size_t)MROWS_C * NCOLS * 2;

    hipMemsetAsync(ws, 0, 512, stream);
    mega<<<GRID_SZ, 256, 0, stream>>>(X, W_in, b_in, W1, b1, W2, b2, W_out, b_out,
                                      out, Bmat, LS0, LS1, G0, G1, fl);
}

// Round 8
// 4919.397 us; speedup vs baseline: 7.3772x; 7.3772x over previous
//
#include <hip/hip_runtime.h>
#include <hip/hip_bf16.h>
#include <cstdint>
#include <cstddef>

// Problem constants
#define B_SZ   256
#define T_SZ   2049
#define D_SZ   64
#define H_SZ   64
#define MLP_SZ 128
#define NI_SZ  128
#define SEG    16
#define L_SZ   2080
#define OUT_SZ 10

// Pipeline shapes
#define NC      16                 // intervals per chunk
#define NCC     (NI_SZ / NC)       // 8 chunks
#define MROWS_C (NC * B_SZ)        // 4096 GEMM rows per chunk
#define NCOLS   8320               // 8192 (n=d*128+m) + 64 (b2) + 64 pad
#define KDIM    L_SZ               // 2080
#define TILES_M (MROWS_C / 128)    // 32
#define TILES_N (NCOLS / 128)      // 65
#define NTILES  (TILES_M * TILES_N)// 2080
#define WORKERS 640
#define ODEB    128                // ode/logsig blocks, 2 batches each
#define GRID_SZ (WORKERS + ODEB)   // 768 = 3 blocks/CU (guaranteed by launch_bounds)

typedef _Float16 f16x8 __attribute__((ext_vector_type(8)));
typedef float    f32x4 __attribute__((ext_vector_type(4)));

// Cacheline-padded flag groups (hot lines isolated)
struct Flags {
    int bmat_done;      int _p0[63];
    int ls_done[NCC];   int _p1[56];
    int gemm_done[NCC]; int _p2[56];
    int ode_done[NCC];  int _p3[56];
    int tile_ctr[NCC];  int _p4[56];
};                                     // 1280 B

union SharedU {
    struct { unsigned short As[128 * 32]; unsigned short Bs[128 * 32]; } g;   // 16 KB
    struct { float seg[SEG + 1][D_SZ]; float cum[SEG][D_SZ];
             float dlt[SEG][D_SZ];     float Mm[D_SZ][D_SZ + 1]; } l;         // 29.2 KB
    struct { float ysw[4][D_SZ]; float part[2][4][D_SZ]; float xb[D_SZ]; } o; // 4.5 KB
};

__device__ __forceinline__ float rlane(float v, int l) {
    return __uint_as_float(__builtin_amdgcn_readlane(__float_as_uint(v), l));
}

// Release: drain block stores (syncthreads waits vmcnt), ONE fence (L2 wb),
// then RELAXED agent-scope RMW (fence orders it after the wb).
__device__ __forceinline__ void sig_release(int* p) {
    __syncthreads();
    if (threadIdx.x == 0) {
        __threadfence();
        __hip_atomic_fetch_add(p, 1, __ATOMIC_RELAXED, __HIP_MEMORY_SCOPE_AGENT);
    }
}
// Wait: RELAXED polls (no per-poll cache invalidation — the R7 killer was
// ACQUIRE-per-poll emitting a full XCD-L2 buffer_inv each iteration),
// then ONE fence (inv) after success.
__device__ __forceinline__ void wait_acquire(int* p, int target) {
    if (threadIdx.x == 0) {
        while (__hip_atomic_load(p, __ATOMIC_RELAXED, __HIP_MEMORY_SCOPE_AGENT) < target)
            __builtin_amdgcn_s_sleep(32);
        __threadfence();
    }
    __syncthreads();
}

// ---------------------------------------------------------------------------
// One logsig job (interval n_global, batch b) -> LS chunk row sl*256+b. 256 thr.
// ---------------------------------------------------------------------------
__device__ void logsig_job(const float* __restrict__ X, _Float16* __restrict__ LSc,
                           int n_global, int sl, int b, SharedU& sh) {
    const int t = threadIdx.x;
    __syncthreads();                       // protect union vs previous phase
    const float* Xp = X + ((size_t)b * T_SZ + (size_t)n_global * SEG) * D_SZ;
    for (int i = t; i < (SEG + 1) * D_SZ / 4; i += 256)
        ((float4*)&sh.l.seg[0][0])[i] = ((const float4*)Xp)[i];
    __syncthreads();
    for (int i = t; i < SEG * D_SZ; i += 256) {
        const int k = i >> 6, d = i & 63;
        sh.l.cum[k][d] = sh.l.seg[k][d] - sh.l.seg[0][d];
        sh.l.dlt[k][d] = sh.l.seg[k + 1][d] - sh.l.seg[k][d];
    }
    __syncthreads();

    const int ti = t >> 4, tj = t & 15;
    const int i0 = ti * 4, j0 = tj * 4;
    float m4[4][4] = {};
#pragma unroll
    for (int k = 0; k < SEG; ++k) {
        const float4 ci = *(const float4*)&sh.l.cum[k][i0];
        const float4 dj = *(const float4*)&sh.l.dlt[k][j0];
        const float* cip = (const float*)&ci;
        const float* djp = (const float*)&dj;
#pragma unroll
        for (int a = 0; a < 4; ++a)
#pragma unroll
            for (int c2 = 0; c2 < 4; ++c2)
                m4[a][c2] += cip[a] * djp[c2];
    }
#pragma unroll
    for (int a = 0; a < 4; ++a)
#pragma unroll
        for (int c2 = 0; c2 < 4; ++c2)
            sh.l.Mm[i0 + a][j0 + c2] = m4[a][c2];
    __syncthreads();

    _Float16* out = LSc + (size_t)(sl * B_SZ + b) * KDIM;
    if (t < D_SZ) out[t] = (_Float16)(sh.l.seg[SEG][t] - sh.l.seg[0][t]);
    if (tj >= ti) {
#pragma unroll
        for (int a = 0; a < 4; ++a) {
            const int i = i0 + a;
#pragma unroll
            for (int c2 = 0; c2 < 4; ++c2) {
                const int j = j0 + c2;
                if (j > i) {
                    const int p = 63 * i - (i * (i - 1)) / 2 + (j - i - 1);
                    out[D_SZ + p] = (_Float16)(0.5f * (m4[a][c2] - sh.l.Mm[j][i]));
                }
            }
        }
    }
    __syncthreads();
}

// ---------------------------------------------------------------------------
// One 128x128 GEMM tile (m97 structure + XOR k-chunk swizzle). 256 thr.
// ---------------------------------------------------------------------------
__device__ void gemm_tile(const unsigned short* __restrict__ A,
                          const unsigned short* __restrict__ Bm,
                          _Float16* __restrict__ C, int bx, int by, SharedU& sh) {
    constexpr int K = KDIM, N = NCOLS;
    const int t = threadIdx.x;
    const int lane = t & 63;
    const int w = t >> 6;
    const int wm = w & 1, wn = w >> 1;
    const int tileM = bx * 128;
    const int tileN = by * 128;

    const int c0 = w * 2, c1 = c0 + 1;
    const int rs0 = c0 * 16 + (lane >> 2);
    const int rs1 = c1 * 16 + (lane >> 2);
    const int kc = (((lane & 3) ^ ((lane >> 2) & 3))) * 8;

    const unsigned short* gA0 = A + (size_t)(tileM + rs0) * K + kc;
    const unsigned short* gA1 = A + (size_t)(tileM + rs1) * K + kc;
    const unsigned short* gB0 = Bm + (size_t)(tileN + rs0) * K + kc;
    const unsigned short* gB1 = Bm + (size_t)(tileN + rs1) * K + kc;
    unsigned short* lA0 = sh.g.As + c0 * 512 + lane * 8;
    unsigned short* lA1 = sh.g.As + c1 * 512 + lane * 8;
    unsigned short* lB0 = sh.g.Bs + c0 * 512 + lane * 8;
    unsigned short* lB1 = sh.g.Bs + c1 * 512 + lane * 8;

    f32x4 acc[4][4] = {};
    const int frow = lane & 15;
    const int fkswz = (((lane >> 4) ^ (frow & 3))) * 8;

    for (int k0 = 0; k0 < K; k0 += 32) {
        __syncthreads();
        __builtin_amdgcn_global_load_lds((__attribute__((address_space(1))) void*)(gA0 + k0),
                                         (__attribute__((address_space(3))) void*)lA0, 16, 0, 0);
        __builtin_amdgcn_global_load_lds((__attribute__((address_space(1))) void*)(gA1 + k0),
                                         (__attribute__((address_space(3))) void*)lA1, 16, 0, 0);
        __builtin_amdgcn_global_load_lds((__attribute__((address_space(1))) void*)(gB0 + k0),
                                         (__attribute__((address_space(3))) void*)lB0, 16, 0, 0);
        __builtin_amdgcn_global_load_lds((__attribute__((address_space(1))) void*)(gB1 + k0),
                                         (__attribute__((address_space(3))) void*)lB1, 16, 0, 0);
        __syncthreads();

        f16x8 af[4], bfm[4];
#pragma unroll
        for (int mi = 0; mi < 4; ++mi)
            af[mi] = *(const f16x8*)(sh.g.As + (wm * 64 + mi * 16 + frow) * 32 + fkswz);
#pragma unroll
        for (int ni = 0; ni < 4; ++ni)
            bfm[ni] = *(const f16x8*)(sh.g.Bs + (wn * 64 + ni * 16 + frow) * 32 + fkswz);
#pragma unroll
        for (int mi = 0; mi < 4; ++mi)
#pragma unroll
            for (int ni = 0; ni < 4; ++ni)
                acc[mi][ni] = __builtin_amdgcn_mfma_f32_16x16x32_f16(af[mi], bfm[ni],
                                                                     acc[mi][ni], 0, 0, 0);
    }

    const int erow = (lane >> 4) * 4;
#pragma unroll
    for (int mi = 0; mi < 4; ++mi)
#pragma unroll
        for (int ni = 0; ni < 4; ++ni) {
            const int col = tileN + wn * 64 + ni * 16 + frow;
            const size_t rbase = (size_t)(tileM + wm * 64 + mi * 16 + erow) * N + col;
#pragma unroll
            for (int r = 0; r < 4; ++r)
                C[rbase + (size_t)r * N] = (_Float16)acc[mi][ni][r];
        }
}

// ---------------------------------------------------------------------------
// Mega persistent kernel: 640 workers (Bmat build + dynamic GEMM tiles) +
// 128 ode/logsig blocks (logsig one chunk ahead; RK4 consume; final out).
// ---------------------------------------------------------------------------
__global__ __launch_bounds__(256, 3) void mega(
        const float* __restrict__ X,    const float* __restrict__ W_in,
        const float* __restrict__ b_in, const float* __restrict__ W1,
        const float* __restrict__ b1,   const float* __restrict__ W2,
        const float* __restrict__ b2,   const float* __restrict__ W_out,
        const float* __restrict__ b_out, float* __restrict__ out,
        _Float16* __restrict__ Bmat, _Float16* __restrict__ LS0, _Float16* __restrict__ LS1,
        _Float16* __restrict__ G0, _Float16* __restrict__ G1, Flags* fl) {
    __shared__ SharedU sh;
    __shared__ int s_tile;
    const int bid = blockIdx.x, t = threadIdx.x;
    _Float16* LSbuf[2] = {LS0, LS1};
    _Float16* Gbuf[2]  = {G0, G1};

    if (bid < WORKERS) {
        // ---------------- worker: Bmat build, then GEMM tiles ----------------
        for (int r = bid; r < NCOLS; r += WORKERS) {
            const float* src = nullptr;
            if (r < 8192) {
                const int d = r >> 7, m = r & 127;
                src = W2 + (size_t)m * (64 * KDIM) + (size_t)d * KDIM;
            } else if (r < 8256) {
                src = b2 + (size_t)(r - 8192) * KDIM;
            }
            _Float16* dst = Bmat + (size_t)r * KDIM;
            for (int l = t; l < KDIM; l += 256)
                dst[l] = src ? (_Float16)src[l] : (_Float16)0.0f;
        }
        sig_release(&fl->bmat_done);
        wait_acquire(&fl->bmat_done, WORKERS);

        for (int c = 0; c < NCC; ++c) {
            if (c >= 2) wait_acquire(&fl->ode_done[c - 2], ODEB);
            wait_acquire(&fl->ls_done[c], ODEB);
            const unsigned short* Ac = (const unsigned short*)LSbuf[c & 1];
            _Float16* Gc = Gbuf[c & 1];
            for (;;) {
                if (t == 0) s_tile = atomicAdd(&fl->tile_ctr[c], 1);
                __syncthreads();
                const int tile = s_tile;
                __syncthreads();
                if (tile >= NTILES) break;
                gemm_tile(Ac, (const unsigned short*)Bmat, Gc,
                          tile % TILES_M, tile / TILES_M, sh);
            }
            sig_release(&fl->gemm_done[c]);
        }
    } else {
        // ---------------- ode/logsig block: 2 batches ----------------
        const int ob = bid - WORKERS;          // 0..127
        const int lane = t & 63, w = t >> 6;
        const int j0 = w * 32 + (lane & 31);
        float w1c[D_SZ];
#pragma unroll
        for (int dd = 0; dd < D_SZ; ++dd) w1c[dd] = W1[dd * MLP_SZ + j0];
        const float b1v = b1[j0];

        float hsv[2];
#pragma unroll
        for (int e = 0; e < 2; ++e) {          // h0
            const int b = ob * 2 + e;
            __syncthreads();
            if (t < D_SZ) sh.o.xb[t] = X[(size_t)b * T_SZ * D_SZ + t];
            __syncthreads();
            float acc = b_in[lane];
            for (int k = 0; k < D_SZ; ++k) acc += sh.o.xb[k] * W_in[k * H_SZ + lane];
            hsv[e] = acc;                      // redundant across waves
        }

        // logsig(0)
        for (int i = 0; i < 32; ++i) {
            const int j = ob * 32 + i;
            logsig_job(X, LSbuf[0], (j >> 8), (j >> 8), j & 255, sh);
        }
        sig_release(&fl->ls_done[0]);

        for (int c = 0; c < NCC; ++c) {
            if (c + 1 < NCC) {                 // logsig one chunk ahead
                for (int i = 0; i < 32; ++i) {
                    const int j = ob * 32 + i;
                    const int sl = j >> 8;
                    logsig_job(X, LSbuf[(c + 1) & 1], (c + 1) * NC + sl, sl, j & 255, sh);
                }
                sig_release(&fl->ls_done[c + 1]);
            }
            wait_acquire(&fl->gemm_done[c], WORKERS);
            const _Float16* Gc = Gbuf[c & 1];

#pragma unroll 1
            for (int e = 0; e < 2; ++e) {
                const int b = ob * 2 + e;
                float h = hsv[e];
                __syncthreads();
                sh.o.ysw[w][lane] = h;
                float k_st[4];
#pragma unroll 1
                for (int s = 0; s < NC; ++s) {
                    const _Float16* Gr = Gc + (size_t)(s * B_SZ + b) * NCOLS;
                    const f16x8* gp = (const f16x8*)(Gr + lane * 128 + w * 32);
                    f16x8 pr[4];
#pragma unroll
                    for (int v = 0; v < 4; ++v) pr[v] = gp[v];
                    const float b2cur = (float)Gr[8192 + lane];
                    float gcur[32];
#pragma unroll
                    for (int v = 0; v < 4; ++v)
#pragma unroll
                        for (int ee = 0; ee < 8; ++ee) gcur[v * 8 + ee] = (float)pr[v][ee];

#pragma unroll
                    for (int st = 0; st < 4; ++st) {
                        float a = 0.0f;
#pragma unroll
                        for (int dd = 0; dd < D_SZ; dd += 4) {
                            const float4 yv = *(const float4*)&sh.o.ysw[w][dd];
                            a += yv.x * w1c[dd] + yv.y * w1c[dd + 1]
                               + yv.z * w1c[dd + 2] + yv.w * w1c[dd + 3];
                        }
                        const float x = b1v + a;
                        const float ex = __expf(2.0f * x);
                        const float z = 1.0f - 2.0f / (ex + 1.0f);
                        float a2 = 0.0f;
#pragma unroll
                        for (int q = 0; q < 32; ++q)
                            a2 += gcur[q] * rlane(z, q);
                        sh.o.part[st & 1][w][lane] = a2;
                        __syncthreads();
                        const float kv = b2cur + sh.o.part[st & 1][0][lane]
                                       + sh.o.part[st & 1][1][lane]
                                       + sh.o.part[st & 1][2][lane]
                                       + sh.o.part[st & 1][3][lane];
                        k_st[st] = kv;
                        if (st < 3) {
                            float y = h;
                            if (st == 0) y += 0.5f * kv;
                            else if (st == 1) y += 0.5f * kv;
                            else y += kv;
                            sh.o.ysw[w][lane] = y;
                        }
                    }
                    h += (k_st[0] + 2.0f * k_st[1] + 2.0f * k_st[2] + k_st[3]) * (1.0f / 6.0f);
                    sh.o.ysw[w][lane] = h;
                }
                hsv[e] = h;
                __syncthreads();
            }
            sig_release(&fl->ode_done[c]);
        }

        // final out for my 2 batches
#pragma unroll
        for (int e = 0; e < 2; ++e) {
            const int b = ob * 2 + e;
            __syncthreads();
            if (w == 0) sh.o.xb[lane] = hsv[e];
            __syncthreads();
            if (t < OUT_SZ) {
                float acc = b_out[t];
                for (int d = 0; d < D_SZ; ++d) acc += sh.o.xb[d] * W_out[d * OUT_SZ + t];
                out[b * OUT_SZ + t] = acc;
            }
        }
    }
}

extern "C" void kernel_launch(void* const* d_in, const int* in_sizes, int n_in,
                              void* d_out, int out_size, void* d_ws, size_t ws_size,
                              hipStream_t stream) {
    (void)in_sizes; (void)n_in; (void)out_size; (void)ws_size;
    const float* X     = (const float*)d_in[0];
    const float* W_in  = (const float*)d_in[1];
    const float* b_in  = (const float*)d_in[2];
    const float* W1    = (const float*)d_in[3];
    const float* b1    = (const float*)d_in[4];
    const float* W2    = (const float*)d_in[5];
    const float* b2    = (const float*)d_in[6];
    const float* W_out = (const float*)d_in[7];
    const float* b_out = (const float*)d_in[8];
    float* out = (float*)d_out;

    // workspace: flags(2KB) + Bmat 34.6MB + LS dbuf 2x17.0MB + G dbuf 2x68.2MB ~ 205MB
    char* ws = (char*)d_ws;
    Flags* fl = (Flags*)ws;
    size_t off = 2048;
    _Float16* Bmat = (_Float16*)(ws + off); off += (size_t)NCOLS * KDIM * 2;
    _Float16* LS0  = (_Float16*)(ws + off); off += (size_t)MROWS_C * KDIM * 2;
    _Float16* LS1  = (_Float16*)(ws + off); off += (size_t)MROWS_C * KDIM * 2;
    _Float16* G0   = (_Float16*)(ws + off); off += (size_t)MROWS_C * NCOLS * 2;
    _Float16* G1   = (_Float16*)(ws + off); off += (size_t)MROWS_C * NCOLS * 2;

    hipMemsetAsync(ws, 0, 2048, stream);
    mega<<<GRID_SZ, 256, 0, stream>>>(X, W_in, b_in, W1, b1, W2, b2, W_out, b_out,
                                      out, Bmat, LS0, LS1, G0, G1, fl);
}

// Round 9
// 3674.943 us; speedup vs baseline: 9.8754x; 1.3386x over previous
//
#include <hip/hip_runtime.h>
#include <hip/hip_bf16.h>
#include <cstdint>
#include <cstddef>

// Problem constants
#define B_SZ   256
#define T_SZ   2049
#define D_SZ   64
#define H_SZ   64
#define MLP_SZ 128
#define NI_SZ  128
#define SEG    16
#define L_SZ   2080
#define OUT_SZ 10

// Pipeline shapes
#define NC      16                 // intervals per chunk
#define NCC     (NI_SZ / NC)       // 8 chunks
#define MROWS_C (NC * B_SZ)        // 4096 GEMM rows per chunk
#define NCOLS   8320               // 8192 (n=d*128+m) + 64 (b2) + 64 pad
#define KDIM    L_SZ               // 2080
#define TILES_M (MROWS_C / 128)    // 32
#define TILES_N (NCOLS / 128)      // 65
#define NTILES  (TILES_M * TILES_N)// 2080
#define LSJOBS  (NC * B_SZ)        // 4096 logsig jobs per chunk

typedef _Float16 f16x8 __attribute__((ext_vector_type(8)));
typedef float    f32x4 __attribute__((ext_vector_type(4)));

union SharedU {
    struct { unsigned short As[128 * 32]; unsigned short Bs[128 * 32]; } g;   // 16 KB
    struct { float seg[SEG + 1][D_SZ]; float cum[SEG][D_SZ];
             float dlt[SEG][D_SZ];     float Mm[D_SZ][D_SZ + 1]; } l;         // 29.2 KB
    struct { float ysw[4][D_SZ]; float part[2][4][D_SZ]; float xb[D_SZ]; } o; // 4.5 KB
};

__device__ __forceinline__ float rlane(float v, int l) {
    return __uint_as_float(__builtin_amdgcn_readlane(__float_as_uint(v), l));
}

// ---------------------------------------------------------------------------
// Role bodies
// ---------------------------------------------------------------------------
__device__ void logsig_role(const float* __restrict__ X, _Float16* __restrict__ LSc,
                            int n_global, int sl, int b, SharedU& sh) {
    const int t = threadIdx.x;
    const float* Xp = X + ((size_t)b * T_SZ + (size_t)n_global * SEG) * D_SZ;
    for (int i = t; i < (SEG + 1) * D_SZ / 4; i += 256)
        ((float4*)&sh.l.seg[0][0])[i] = ((const float4*)Xp)[i];
    __syncthreads();
    for (int i = t; i < SEG * D_SZ; i += 256) {
        const int k = i >> 6, d = i & 63;
        sh.l.cum[k][d] = sh.l.seg[k][d] - sh.l.seg[0][d];
        sh.l.dlt[k][d] = sh.l.seg[k + 1][d] - sh.l.seg[k][d];
    }
    __syncthreads();

    const int ti = t >> 4, tj = t & 15;
    const int i0 = ti * 4, j0 = tj * 4;
    float m4[4][4] = {};
#pragma unroll
    for (int k = 0; k < SEG; ++k) {
        const float4 ci = *(const float4*)&sh.l.cum[k][i0];
        const float4 dj = *(const float4*)&sh.l.dlt[k][j0];
        const float* cip = (const float*)&ci;
        const float* djp = (const float*)&dj;
#pragma unroll
        for (int a = 0; a < 4; ++a)
#pragma unroll
            for (int c2 = 0; c2 < 4; ++c2)
                m4[a][c2] += cip[a] * djp[c2];
    }
#pragma unroll
    for (int a = 0; a < 4; ++a)
#pragma unroll
        for (int c2 = 0; c2 < 4; ++c2)
            sh.l.Mm[i0 + a][j0 + c2] = m4[a][c2];
    __syncthreads();

    _Float16* out = LSc + (size_t)(sl * B_SZ + b) * KDIM;
    if (t < D_SZ) out[t] = (_Float16)(sh.l.seg[SEG][t] - sh.l.seg[0][t]);
    if (tj >= ti) {
#pragma unroll
        for (int a = 0; a < 4; ++a) {
            const int i = i0 + a;
#pragma unroll
            for (int c2 = 0; c2 < 4; ++c2) {
                const int j = j0 + c2;
                if (j > i) {
                    const int p = 63 * i - (i * (i - 1)) / 2 + (j - i - 1);
                    out[D_SZ + p] = (_Float16)(0.5f * (m4[a][c2] - sh.l.Mm[j][i]));
                }
            }
        }
    }
}

__device__ void gemm_role(const unsigned short* __restrict__ A,
                          const unsigned short* __restrict__ Bm,
                          _Float16* __restrict__ C, int bx, int by, SharedU& sh) {
    constexpr int K = KDIM, N = NCOLS;
    const int t = threadIdx.x;
    const int lane = t & 63;
    const int w = t >> 6;
    const int wm = w & 1, wn = w >> 1;
    const int tileM = bx * 128;
    const int tileN = by * 128;

    const int c0 = w * 2, c1 = c0 + 1;
    const int rs0 = c0 * 16 + (lane >> 2);
    const int rs1 = c1 * 16 + (lane >> 2);
    const int kc = (((lane & 3) ^ ((lane >> 2) & 3))) * 8;

    const unsigned short* gA0 = A + (size_t)(tileM + rs0) * K + kc;
    const unsigned short* gA1 = A + (size_t)(tileM + rs1) * K + kc;
    const unsigned short* gB0 = Bm + (size_t)(tileN + rs0) * K + kc;
    const unsigned short* gB1 = Bm + (size_t)(tileN + rs1) * K + kc;
    unsigned short* lA0 = sh.g.As + c0 * 512 + lane * 8;
    unsigned short* lA1 = sh.g.As + c1 * 512 + lane * 8;
    unsigned short* lB0 = sh.g.Bs + c0 * 512 + lane * 8;
    unsigned short* lB1 = sh.g.Bs + c1 * 512 + lane * 8;

    f32x4 acc[4][4] = {};
    const int frow = lane & 15;
    const int fkswz = (((lane >> 4) ^ (frow & 3))) * 8;

    for (int k0 = 0; k0 < K; k0 += 32) {
        __syncthreads();
        __builtin_amdgcn_global_load_lds((__attribute__((address_space(1))) void*)(gA0 + k0),
                                         (__attribute__((address_space(3))) void*)lA0, 16, 0, 0);
        __builtin_amdgcn_global_load_lds((__attribute__((address_space(1))) void*)(gA1 + k0),
                                         (__attribute__((address_space(3))) void*)lA1, 16, 0, 0);
        __builtin_amdgcn_global_load_lds((__attribute__((address_space(1))) void*)(gB0 + k0),
                                         (__attribute__((address_space(3))) void*)lB0, 16, 0, 0);
        __builtin_amdgcn_global_load_lds((__attribute__((address_space(1))) void*)(gB1 + k0),
                                         (__attribute__((address_space(3))) void*)lB1, 16, 0, 0);
        __syncthreads();

        f16x8 af[4], bfm[4];
#pragma unroll
        for (int mi = 0; mi < 4; ++mi)
            af[mi] = *(const f16x8*)(sh.g.As + (wm * 64 + mi * 16 + frow) * 32 + fkswz);
#pragma unroll
        for (int ni = 0; ni < 4; ++ni)
            bfm[ni] = *(const f16x8*)(sh.g.Bs + (wn * 64 + ni * 16 + frow) * 32 + fkswz);
#pragma unroll
        for (int mi = 0; mi < 4; ++mi)
#pragma unroll
            for (int ni = 0; ni < 4; ++ni)
                acc[mi][ni] = __builtin_amdgcn_mfma_f32_16x16x32_f16(af[mi], bfm[ni],
                                                                     acc[mi][ni], 0, 0, 0);
    }

    const int erow = (lane >> 4) * 4;
#pragma unroll
    for (int mi = 0; mi < 4; ++mi)
#pragma unroll
        for (int ni = 0; ni < 4; ++ni) {
            const int col = tileN + wn * 64 + ni * 16 + frow;
            const size_t rbase = (size_t)(tileM + wm * 64 + mi * 16 + erow) * N + col;
#pragma unroll
            for (int r = 0; r < 4; ++r)
                C[rbase + (size_t)r * N] = (_Float16)acc[mi][ni][r];
        }
}

// RK4 over NC steps for batch b; writes h_state, or out when last==1.
__device__ void ode_role(const _Float16* __restrict__ G, const float* __restrict__ W1,
                         const float* __restrict__ b1, float* __restrict__ h_state,
                         const float* __restrict__ W_out, const float* __restrict__ b_out,
                         float* __restrict__ out, int b, int last, SharedU& sh) {
    const int t = threadIdx.x;
    const int lane = t & 63, w = t >> 6;
    const int j0 = w * 32 + (lane & 31);
    float w1c[D_SZ];
#pragma unroll
    for (int dd = 0; dd < D_SZ; ++dd) w1c[dd] = W1[dd * MLP_SZ + j0];
    const float b1v = b1[j0];

    float hsv = h_state[b * H_SZ + lane];      // all waves (redundant)
    sh.o.ysw[w][lane] = hsv;
    float k_st[4];

    f16x8 pr[4];
    _Float16 b2pre;
    {
        const _Float16* Gr = G + (size_t)b * NCOLS;
        const f16x8* gp = (const f16x8*)(Gr + lane * 128 + w * 32);
#pragma unroll
        for (int v = 0; v < 4; ++v) pr[v] = gp[v];
        b2pre = Gr[8192 + lane];
    }

#pragma unroll 1
    for (int s = 0; s < NC; ++s) {
        float gcur[32];
#pragma unroll
        for (int v = 0; v < 4; ++v)
#pragma unroll
            for (int e = 0; e < 8; ++e) gcur[v * 8 + e] = (float)pr[v][e];
        const float b2cur = (float)b2pre;
        if (s + 1 < NC) {                      // prefetch next step
            const _Float16* Gr = G + (size_t)((s + 1) * B_SZ + b) * NCOLS;
            const f16x8* gp = (const f16x8*)(Gr + lane * 128 + w * 32);
#pragma unroll
            for (int v = 0; v < 4; ++v) pr[v] = gp[v];
            b2pre = Gr[8192 + lane];
        }

#pragma unroll
        for (int st = 0; st < 4; ++st) {
            float a = 0.0f;
#pragma unroll
            for (int dd = 0; dd < D_SZ; dd += 4) {
                const float4 yv = *(const float4*)&sh.o.ysw[w][dd];
                a += yv.x * w1c[dd] + yv.y * w1c[dd + 1]
                   + yv.z * w1c[dd + 2] + yv.w * w1c[dd + 3];
            }
            const float x = b1v + a;
            const float ex = __expf(2.0f * x);
            const float z = 1.0f - 2.0f / (ex + 1.0f);
            float a2 = 0.0f;
#pragma unroll
            for (int q = 0; q < 32; ++q)
                a2 += gcur[q] * rlane(z, q);
            sh.o.part[st & 1][w][lane] = a2;
            __syncthreads();
            const float kv = b2cur + sh.o.part[st & 1][0][lane]
                           + sh.o.part[st & 1][1][lane]
                           + sh.o.part[st & 1][2][lane]
                           + sh.o.part[st & 1][3][lane];
            k_st[st] = kv;
            if (st < 3) {
                float y = hsv;
                if (st == 0) y += 0.5f * kv;
                else if (st == 1) y += 0.5f * kv;
                else y += kv;
                sh.o.ysw[w][lane] = y;
            }
        }
        hsv += (k_st[0] + 2.0f * k_st[1] + 2.0f * k_st[2] + k_st[3]) * (1.0f / 6.0f);
        sh.o.ysw[w][lane] = hsv;
    }
    if (!last) {
        if (w == 0) h_state[b * H_SZ + lane] = hsv;
    } else {
        // out = hT @ W_out + b_out  (ysw[0][*] holds final h; wave 0 reads own writes)
        if (t < OUT_SZ) {
            float acc = b_out[t];
            for (int d = 0; d < D_SZ; ++d) acc += sh.o.ysw[0][d] * W_out[d * OUT_SZ + t];
            out[b * OUT_SZ + t] = acc;
        }
    }
}

// ---------------------------------------------------------------------------
// One fused dispatch: [ode(oc)] + [gemm(gc)] + [logsig(lc)] + [prep: Bmat+h0].
// All dependencies are across dispatch boundaries (in-order stream) — no
// flags, no fences, no cross-block sync (the R7/R8 L2-storm killer removed).
// ---------------------------------------------------------------------------
__global__ __launch_bounds__(256) void fused(
        const float* __restrict__ X,    const float* __restrict__ W_in,
        const float* __restrict__ b_in, const float* __restrict__ W1,
        const float* __restrict__ b1,   const float* __restrict__ W2,
        const float* __restrict__ b2,   const float* __restrict__ W_out,
        const float* __restrict__ b_out, float* __restrict__ out,
        _Float16* __restrict__ Bmat, _Float16* __restrict__ LS0, _Float16* __restrict__ LS1,
        _Float16* __restrict__ G0, _Float16* __restrict__ G1,
        float* __restrict__ hst, int oc, int gc, int lc, int prep) {
    __shared__ SharedU sh;
    int idx = blockIdx.x;
    const int t = threadIdx.x;

    if (oc >= 0) {
        if (idx < B_SZ) {
            ode_role(((oc & 1) ? G1 : G0), W1, b1, hst, W_out, b_out, out,
                     idx, oc == NCC - 1, sh);
            return;
        }
        idx -= B_SZ;
    }
    if (gc >= 0) {
        if (idx < NTILES) {
            gemm_role((const unsigned short*)((gc & 1) ? LS1 : LS0),
                      (const unsigned short*)Bmat, ((gc & 1) ? G1 : G0),
                      idx % TILES_M, idx / TILES_M, sh);
            return;
        }
        idx -= NTILES;
    }
    if (lc >= 0) {
        if (idx < LSJOBS) {
            const int sl = idx >> 8, b = idx & 255;
            logsig_role(X, ((lc & 1) ? LS1 : LS0), lc * NC + sl, sl, b, sh);
            return;
        }
        idx -= LSJOBS;
    }
    if (prep) {
        if (idx < NCOLS) {                    // Bmat row idx (permuted n = d*128+m)
            const int r = idx;
            const float* src = nullptr;
            if (r < 8192) {
                const int d = r >> 7, m = r & 127;
                src = W2 + (size_t)m * (64 * KDIM) + (size_t)d * KDIM;
            } else if (r < 8256) {
                src = b2 + (size_t)(r - 8192) * KDIM;
            }
            _Float16* dst = Bmat + (size_t)r * KDIM;
            for (int l = t; l < KDIM; l += 256)
                dst[l] = src ? (_Float16)src[l] : (_Float16)0.0f;
            return;
        }
        idx -= NCOLS;
        if (idx < B_SZ) {                     // h0 for batch idx
            const int b = idx;
            if (t < D_SZ) sh.o.xb[t] = X[(size_t)b * T_SZ * D_SZ + t];
            __syncthreads();
            if (t < H_SZ) {
                float acc = b_in[t];
                for (int k = 0; k < D_SZ; ++k) acc += sh.o.xb[k] * W_in[k * H_SZ + t];
                hst[b * H_SZ + t] = acc;
            }
        }
    }
}

extern "C" void kernel_launch(void* const* d_in, const int* in_sizes, int n_in,
                              void* d_out, int out_size, void* d_ws, size_t ws_size,
                              hipStream_t stream) {
    (void)in_sizes; (void)n_in; (void)out_size; (void)ws_size;
    const float* X     = (const float*)d_in[0];
    const float* W_in  = (const float*)d_in[1];
    const float* b_in  = (const float*)d_in[2];
    const float* W1    = (const float*)d_in[3];
    const float* b1    = (const float*)d_in[4];
    const float* W2    = (const float*)d_in[5];
    const float* b2    = (const float*)d_in[6];
    const float* W_out = (const float*)d_in[7];
    const float* b_out = (const float*)d_in[8];
    float* out = (float*)d_out;

    // workspace: Bmat 34.6 + LS dbuf 2x17.0 + G dbuf 2x68.2 + hst ~ 205 MB
    char* ws = (char*)d_ws;
    size_t off = 0;
    auto take = [&](size_t bytes) { void* p = ws + off; off = (off + bytes + 255) & ~(size_t)255; return p; };
    _Float16* Bmat = (_Float16*)take((size_t)NCOLS * KDIM * 2);
    _Float16* LS0  = (_Float16*)take((size_t)MROWS_C * KDIM * 2);
    _Float16* LS1  = (_Float16*)take((size_t)MROWS_C * KDIM * 2);
    _Float16* G0   = (_Float16*)take((size_t)MROWS_C * NCOLS * 2);
    _Float16* G1   = (_Float16*)take((size_t)MROWS_C * NCOLS * 2);
    float*    hst  = (float*)take((size_t)B_SZ * H_SZ * 4);

    for (int i = 0; i <= 9; ++i) {
        const int oc   = (i >= 2) ? i - 2 : -1;            // 0..7 at i=2..9
        const int gc   = (i >= 1 && i <= 8) ? i - 1 : -1;  // 0..7 at i=1..8
        const int lc   = (i <= 7) ? i : -1;                // 0..7 at i=0..7
        const int prep = (i == 0) ? 1 : 0;
        int grid = 0;
        if (oc >= 0) grid += B_SZ;
        if (gc >= 0) grid += NTILES;
        if (lc >= 0) grid += LSJOBS;
        if (prep)    grid += NCOLS + B_SZ;
        fused<<<grid, 256, 0, stream>>>(X, W_in, b_in, W1, b1, W2, b2, W_out, b_out,
                                        out, Bmat, LS0, LS1, G0, G1, hst,
                                        oc, gc, lc, prep);
    }
}